// Round 17
// baseline (516.646 us; speedup 1.0000x reference)
//
#include <hip/hip_runtime.h>
#include <stdint.h>
#include <stddef.h>

typedef __bf16 bf16_t;
typedef __bf16 bf16x4 __attribute__((ext_vector_type(4)));
typedef __bf16 bf16x8 __attribute__((ext_vector_type(8)));
typedef float f32x4 __attribute__((ext_vector_type(4)));

#define DEV static __device__ __forceinline__

static constexpr int kB = 8, kT = 1024, kC = 1024, kM = 8192, kH = 16, kHD = 64, kFF = 4096;

DEV f32x4 mfma16(bf16x8 a, bf16x8 b, f32x4 c) {
  return __builtin_amdgcn_mfma_f32_16x16x32_bf16(a, b, c, 0, 0, 0);
}

// raw hardware exp2 (D = 2^S0); inputs always <= 0 here.
DEV float ex2(float x) {
  float r;
  asm("v_exp_f32 %0, %1" : "=v"(r) : "v"(x));
  return r;
}

// async global->LDS, 16B per lane. LDS dest must be wave-uniform base (+lane*16 by HW).
DEV void gload_lds16(const void* g, void* l) {
  __builtin_amdgcn_global_load_lds(
      reinterpret_cast<const __attribute__((address_space(1))) void*>(
          reinterpret_cast<uintptr_t>(g)),
      reinterpret_cast<__attribute__((address_space(3))) void*>(
          static_cast<uint32_t>(reinterpret_cast<uintptr_t>(l))),
      16, 0, 0);
}

// ---------------- cast f32 -> bf16 ----------------
__global__ void k_cast_bf16(const float* __restrict__ in, bf16_t* __restrict__ out, int n4) {
  int i = blockIdx.x * blockDim.x + threadIdx.x;
  if (i >= n4) return;
  float4 v = reinterpret_cast<const float4*>(in)[i];
  bf16x4 o;
  o[0] = (bf16_t)v.x; o[1] = (bf16_t)v.y; o[2] = (bf16_t)v.z; o[3] = (bf16_t)v.w;
  reinterpret_cast<bf16x4*>(out)[i] = o;
}

// ---------- batched transpose+cast: 8x f32[1024][1024] -> bf16[1024][1024]^T ----------
struct Trans8Args { const float* src[8]; bf16_t* dst[8]; };
__global__ void k_transpose_cast8(Trans8Args a) {
  __shared__ float tile[32][33];
  const float* __restrict__ in = a.src[blockIdx.z];
  bf16_t* __restrict__ out = a.dst[blockIdx.z];
  int c0 = blockIdx.x * 32, r0 = blockIdx.y * 32;
  int tx = threadIdx.x, ty = threadIdx.y;  // (32,8)
#pragma unroll
  for (int i = 0; i < 4; ++i)
    tile[ty + 8 * i][tx] = in[(size_t)(r0 + ty + 8 * i) * kC + c0 + tx];
  __syncthreads();
#pragma unroll
  for (int i = 0; i < 4; ++i)
    out[(size_t)(c0 + ty + 8 * i) * kC + r0 + tx] = (bf16_t)tile[tx][ty + 8 * i];
}

// ---------- transpose+cast f32[R][C] -> bf16[C][R] ----------
__global__ void k_transpose_cast(const float* __restrict__ in, bf16_t* __restrict__ out,
                                 int R, int C) {
  __shared__ float tile[32][33];
  int c0 = blockIdx.x * 32, r0 = blockIdx.y * 32;
  int tx = threadIdx.x, ty = threadIdx.y;  // (32,8)
#pragma unroll
  for (int i = 0; i < 4; ++i)
    tile[ty + 8 * i][tx] = in[(size_t)(r0 + ty + 8 * i) * C + c0 + tx];
  __syncthreads();
#pragma unroll
  for (int i = 0; i < 4; ++i)
    out[(size_t)(c0 + ty + 8 * i) * R + r0 + tx] = (bf16_t)tile[tx][ty + 8 * i];
}

// ---------------- layernorm f32 -> bf16 (one block per row of 1024) ----------------
template <bool CASTX>
__global__ __launch_bounds__(256) void k_ln(const float* __restrict__ in,
                                            const float* __restrict__ g,
                                            const float* __restrict__ b,
                                            bf16_t* __restrict__ out,
                                            bf16_t* __restrict__ rawout) {
  int row = blockIdx.x, t = threadIdx.x;
  const float4 v = reinterpret_cast<const float4*>(in + (size_t)row * kC)[t];
  if constexpr (CASTX) {
    bf16x4 c;
    c[0] = (bf16_t)v.x; c[1] = (bf16_t)v.y; c[2] = (bf16_t)v.z; c[3] = (bf16_t)v.w;
    reinterpret_cast<bf16x4*>(rawout + (size_t)row * kC)[t] = c;
  }
  float s = v.x + v.y + v.z + v.w;
  float ss = v.x * v.x + v.y * v.y + v.z * v.z + v.w * v.w;
#pragma unroll
  for (int off = 1; off < 64; off <<= 1) {
    s += __shfl_xor(s, off, 64);
    ss += __shfl_xor(ss, off, 64);
  }
  __shared__ float rs[4], rss[4];
  int w = t >> 6;
  if ((t & 63) == 0) { rs[w] = s; rss[w] = ss; }
  __syncthreads();
  s = rs[0] + rs[1] + rs[2] + rs[3];
  ss = rss[0] + rss[1] + rss[2] + rss[3];
  float mean = s * (1.f / kC);
  float var = ss * (1.f / kC) - mean * mean;
  float rstd = rsqrtf(var + 1e-5f);
  float4 gv = reinterpret_cast<const float4*>(g)[t];
  float4 bv = reinterpret_cast<const float4*>(b)[t];
  bf16x4 o;
  o[0] = (bf16_t)((v.x - mean) * rstd * gv.x + bv.x);
  o[1] = (bf16_t)((v.y - mean) * rstd * gv.y + bv.y);
  o[2] = (bf16_t)((v.z - mean) * rstd * gv.z + bv.z);
  o[3] = (bf16_t)((v.w - mean) * rstd * gv.w + bv.w);
  reinterpret_cast<bf16x4*>(out + (size_t)row * kC)[t] = o;
}

// ============ GEMM v4.3: 128x128, 2 blocks/CU, XCD-chunked + in-band order ============
// As R16 (proven) + nontemporal epilogue stores (outputs are read-once-streaming by
// their consumers; kills the write-allocate over-fetch: FF1 FETCH 65MB vs 24MB unique).
// EPI: 0 = bf16 out; 1 = f32 out + bias + residual; 2 = bf16 out + bias + ReLU;
//      3 = bf16 transposed out (ld M); 4 = split KV
template <int EPI, bool YFAST>
__global__ __launch_bounds__(256, 2) void k_gemm2(
    const bf16_t* __restrict__ A, const bf16_t* __restrict__ Bt,
    const float* __restrict__ bias, const float* __restrict__ res,
    float* __restrict__ outf, bf16_t* __restrict__ outb, bf16_t* __restrict__ outb2,
    int M, int N, int K) {
  extern __shared__ bf16_t smem[];
  bf16_t* As = smem;                  // 2 x 128x64 (8192 el / buf)
  bf16_t* Bs = smem + 2 * 8192;       // 2 x 128x64
  const int t = threadIdx.x;
  const int w = t >> 6, lane = t & 63;
  const int l15 = lane & 15, l4 = lane >> 4;
  const int wr = w >> 1, wc = w & 1;

  // XCD-chunked bijective remap; in-band order per YFAST.
  const int gx = gridDim.x;
  const int nwg = gx * gridDim.y;
  const int lid = blockIdx.y * gx + blockIdx.x;
  const int band = lid & 7;
  const int tin = lid >> 3;
  int txi, tyi;
  if (YFAST) {
    txi = tin >> 3;
    tyi = band * 8 + (tin & 7);
  } else {
    const int tile = band * (nwg >> 3) + tin;
    txi = tile % gx;
    tyi = tile / gx;
  }
  const int bm0 = tyi * 128, bn0 = txi * 128;

  f32x4 acc[4][4] = {};

  const int srow = w * 8 + (lane >> 3);
  const int scol = ((lane & 7) ^ (lane >> 3)) * 8;
  const bf16_t* aSrc0 = A + (size_t)(bm0 + srow) * K + scol;
  const bf16_t* bSrc0 = Bt + (size_t)(bn0 + srow) * K + scol;
  const size_t r32 = (size_t)32 * K;

  const int arow = wr * 64 + l15;
  const int brow = wc * 64 + l15;
  const int cbx = (l15 & 7) * 16;
  const int cbe0 = ((l4 * 16) ^ cbx) >> 1;
  const int cbe1 = ((64 | (l4 * 16)) ^ cbx) >> 1;

  const int nkt = K >> 6;

  auto stage = [&](int tt, int bi) {
    const size_t ko = (size_t)tt * 64;
    bf16_t* da = As + bi * 8192 + w * 512;
    bf16_t* db = Bs + bi * 8192 + w * 512;
#pragma unroll
    for (int c = 0; c < 4; ++c) {
      gload_lds16(aSrc0 + ko + (size_t)c * r32, da + c * 2048);
      gload_lds16(bSrc0 + ko + (size_t)c * r32, db + c * 2048);
    }
  };

  stage(0, 0);
  asm volatile("s_waitcnt vmcnt(0)" ::: "memory");
  __builtin_amdgcn_s_barrier();

  int bi = 0;
  for (int tt = 0; tt < nkt; ++tt) {
    if (tt + 1 < nkt) stage(tt + 1, bi ^ 1);
    const bf16_t* bA = As + bi * 8192;
    const bf16_t* bB = Bs + bi * 8192;
    bf16x8 af[4], bfr[4];
#pragma unroll
    for (int m = 0; m < 4; ++m)
      af[m] = *reinterpret_cast<const bf16x8*>(&bA[(arow + m * 16) * 64 + cbe0]);
#pragma unroll
    for (int n = 0; n < 4; ++n)
      bfr[n] = *reinterpret_cast<const bf16x8*>(&bB[(brow + n * 16) * 64 + cbe0]);
    __builtin_amdgcn_s_setprio(1);
#pragma unroll
    for (int m = 0; m < 4; ++m)
#pragma unroll
      for (int n = 0; n < 4; ++n) acc[m][n] = mfma16(af[m], bfr[n], acc[m][n]);
    __builtin_amdgcn_s_setprio(0);
#pragma unroll
    for (int m = 0; m < 4; ++m)
      af[m] = *reinterpret_cast<const bf16x8*>(&bA[(arow + m * 16) * 64 + cbe1]);
#pragma unroll
    for (int n = 0; n < 4; ++n)
      bfr[n] = *reinterpret_cast<const bf16x8*>(&bB[(brow + n * 16) * 64 + cbe1]);
    __builtin_amdgcn_s_setprio(1);
#pragma unroll
    for (int m = 0; m < 4; ++m)
#pragma unroll
      for (int n = 0; n < 4; ++n) acc[m][n] = mfma16(af[m], bfr[n], acc[m][n]);
    __builtin_amdgcn_s_setprio(0);
    if (tt + 1 < nkt) {
      asm volatile("s_waitcnt vmcnt(0)" ::: "memory");
      __builtin_amdgcn_s_barrier();
    }
    bi ^= 1;
  }

  const int gm = bm0 + wr * 64 + l4 * 4;
  const int gn = bn0 + wc * 64 + l15;
  if constexpr (EPI == 0) {
#pragma unroll
    for (int m = 0; m < 4; ++m)
#pragma unroll
      for (int n = 0; n < 4; ++n)
#pragma unroll
        for (int r = 0; r < 4; ++r)
          __builtin_nontemporal_store(
              (bf16_t)acc[m][n][r], &outb[(size_t)(gm + m * 16 + r) * N + (gn + n * 16)]);
  } else if constexpr (EPI == 1) {
#pragma unroll
    for (int m = 0; m < 4; ++m)
#pragma unroll
      for (int n = 0; n < 4; ++n) {
        const int col = gn + n * 16;
        const float bv = bias[col];
#pragma unroll
        for (int r = 0; r < 4; ++r) {
          const size_t idx = (size_t)(gm + m * 16 + r) * N + col;
          __builtin_nontemporal_store(acc[m][n][r] + bv + res[idx], &outf[idx]);
        }
      }
  } else if constexpr (EPI == 2) {
#pragma unroll
    for (int m = 0; m < 4; ++m)
#pragma unroll
      for (int n = 0; n < 4; ++n) {
        const int col = gn + n * 16;
        const float bv = bias[col];
#pragma unroll
        for (int r = 0; r < 4; ++r) {
          float v = acc[m][n][r] + bv;
          v = fmaxf(v, 0.f);
          __builtin_nontemporal_store((bf16_t)v,
                                      &outb[(size_t)(gm + m * 16 + r) * N + col]);
        }
      }
  } else if constexpr (EPI == 3) {
#pragma unroll
    for (int m = 0; m < 4; ++m)
#pragma unroll
      for (int n = 0; n < 4; ++n) {
        bf16x4 ov;
#pragma unroll
        for (int r = 0; r < 4; ++r) ov[r] = (bf16_t)acc[m][n][r];
        __builtin_nontemporal_store(
            ov, reinterpret_cast<bf16x4*>(&outb[(size_t)(gn + n * 16) * M + gm + m * 16]));
      }
  } else {  // EPI == 4: split KV (block-uniform: bn0 multiple of 128)
    const int half = N >> 1;
    if (bn0 < half) {
#pragma unroll
      for (int m = 0; m < 4; ++m)
#pragma unroll
        for (int n = 0; n < 4; ++n)
#pragma unroll
          for (int r = 0; r < 4; ++r)
            __builtin_nontemporal_store(
                (bf16_t)acc[m][n][r],
                &outb[(size_t)(gm + m * 16 + r) * half + (gn + n * 16)]);
    } else {
#pragma unroll
      for (int m = 0; m < 4; ++m)
#pragma unroll
        for (int n = 0; n < 4; ++n) {
          bf16x4 ov;
#pragma unroll
          for (int r = 0; r < 4; ++r) ov[r] = (bf16_t)acc[m][n][r];
          __builtin_nontemporal_store(
              ov, reinterpret_cast<bf16x4*>(
                      &outb2[(size_t)(gn + n * 16 - half) * M + gm + m * 16]));
        }
    }
  }
}

// ---------------- flash attention v3: 512-thread blocks, 256 q-rows ----------------
// Grid (b, h, qseg): 8 waves, wave w owns q-rows qseg*256 + w*32. K/V staged once per
// 256 q-rows (2 gloads/wave/tile, was 4 per 128 rows); LDS 68KB -> 2 blocks/CU x 8
// waves = 16 waves/CU (was 12). Same per-wave math/barrier structure as R10 (proven).
// CAUSAL: qseg reversed (longest-first); per-wave gating at klim.
template <bool CAUSAL>
__global__ __launch_bounds__(512) void k_attn(const bf16_t* __restrict__ Q,
                                              const bf16_t* __restrict__ Kb,
                                              const bf16_t* __restrict__ Vt,
                                              bf16_t* __restrict__ O) {
  __shared__ bf16_t Ks[2][4096];   // [buf][64 key-rows][64 d-el], swizzled rows
  __shared__ bf16_t Vs[2][4096];   // [buf][64 d-rows][64 key-el], swizzled rows
  __shared__ bf16_t P[8][32][72];  // per-wave P buffer
  const int b = blockIdx.x, h = blockIdx.y;
  const int w = threadIdx.x >> 6, lane = threadIdx.x & 63;
  const int l15 = lane & 15, l4 = lane >> 4;
  const int qseg = CAUSAL ? (kT / 256 - 1 - blockIdx.z) : blockIdx.z;
  const int qr0 = qseg * 256 + w * 32;  // this wave's first q-row

  bf16x8 qf[2][2];
#pragma unroll
  for (int a = 0; a < 2; ++a) {
    const bf16_t* qp = Q + (size_t)(b * kT + qr0 + a * 16 + l15) * kC + h * kHD + l4 * 8;
    qf[a][0] = *reinterpret_cast<const bf16x8*>(qp);
    qf[a][1] = *reinterpret_cast<const bf16x8*>(qp + 32);
#pragma unroll
    for (int j = 0; j < 8; ++j) {
      qf[a][0][j] = (bf16_t)((float)qf[a][0][j] * 0.1803368801111204f);
      qf[a][1][j] = (bf16_t)((float)qf[a][1][j] * 0.1803368801111204f);
    }
  }
  bf16x8 ones;
#pragma unroll
  for (int j = 0; j < 8; ++j) ones[j] = (bf16_t)1.0f;

  f32x4 po[2][4] = {};
  f32x4 po_s[2] = {};
  float mrun[2];
  mrun[0] = mrun[1] = -3.0e38f;

  const int nkt = CAUSAL ? 4 * qseg + 4 : (kT / 64);
  const int klim = CAUSAL ? ((qr0 + 31) >> 6) : (1 << 30);

  // staging: wave w covers rows w*8 + lr (8 rows) of the 64-row tile; pre-swizzled col
  const int lr = lane >> 3;
  const int cswz = ((lane & 7) ^ lr) * 8;
  const bf16_t* kSrc = Kb + (size_t)(b * kT + w * 8 + lr) * kC + h * kHD + cswz;
  const bf16_t* vSrc = Vt + (size_t)(h * kHD + w * 8 + lr) * (kB * kT) + b * kT + cswz;

  auto stage = [&](int kt, int buf) {
    gload_lds16(kSrc + (size_t)kt * 64 * kC, &Ks[buf][w * 512]);
    gload_lds16(vSrc + (size_t)kt * 64,      &Vs[buf][w * 512]);
  };

  const int cbx = (l15 & 7) * 16;
  const int rb0 = ((l4 * 16) ^ cbx) >> 1;
  const int rb1 = ((64 | (l4 * 16)) ^ cbx) >> 1;

  stage(0, 0);
  asm volatile("s_waitcnt vmcnt(0)" ::: "memory");
  __builtin_amdgcn_s_barrier();

  int buf = 0;
  for (int kt = 0; kt < nkt; ++kt) {
    if (kt + 1 < nkt) stage(kt + 1, buf ^ 1);
    if (kt <= klim) {
      bf16x8 kf[4][2];
#pragma unroll
      for (int sub = 0; sub < 4; ++sub) {
        kf[sub][0] = *reinterpret_cast<const bf16x8*>(&Ks[buf][(sub * 16 + l15) * 64 + rb0]);
        kf[sub][1] = *reinterpret_cast<const bf16x8*>(&Ks[buf][(sub * 16 + l15) * 64 + rb1]);
      }
      bf16x8 vf[2][4];
#pragma unroll
      for (int n = 0; n < 4; ++n) {
        vf[0][n] = *reinterpret_cast<const bf16x8*>(&Vs[buf][(n * 16 + l15) * 64 + rb0]);
        vf[1][n] = *reinterpret_cast<const bf16x8*>(&Vs[buf][(n * 16 + l15) * 64 + rb1]);
      }

      f32x4 s[2][4] = {};
      __builtin_amdgcn_s_setprio(1);
#pragma unroll
      for (int a = 0; a < 2; ++a)
#pragma unroll
        for (int sub = 0; sub < 4; ++sub) {
          s[a][sub] = mfma16(kf[sub][0], qf[a][0], s[a][sub]);
          s[a][sub] = mfma16(kf[sub][1], qf[a][1], s[a][sub]);
        }
      __builtin_amdgcn_s_setprio(0);
      if (CAUSAL && kt == klim) {
#pragma unroll
        for (int a = 0; a < 2; ++a) {
          const int qrow = qr0 + a * 16 + l15;
#pragma unroll
          for (int sub = 0; sub < 4; ++sub)
#pragma unroll
            for (int r = 0; r < 4; ++r) {
              const int key = kt * 64 + sub * 16 + l4 * 4 + r;
              if (key > qrow) s[a][sub][r] = -3.0e38f;
            }
        }
      }
#pragma unroll
      for (int a = 0; a < 2; ++a) {
        float t0 = fmaxf(fmaxf(s[a][0][0], s[a][0][1]), fmaxf(s[a][0][2], s[a][0][3]));
        float t1 = fmaxf(fmaxf(s[a][1][0], s[a][1][1]), fmaxf(s[a][1][2], s[a][1][3]));
        float t2 = fmaxf(fmaxf(s[a][2][0], s[a][2][1]), fmaxf(s[a][2][2], s[a][2][3]));
        float t3 = fmaxf(fmaxf(s[a][3][0], s[a][3][1]), fmaxf(s[a][3][2], s[a][3][3]));
        float v = fmaxf(fmaxf(t0, t1), fmaxf(t2, t3));
        v = fmaxf(v, __shfl_xor(v, 16, 64));
        v = fmaxf(v, __shfl_xor(v, 32, 64));
        if (!__all(v <= mrun[a] + 8.f)) {
          const float mnew = fmaxf(mrun[a], v);
          const float corr = ex2(mrun[a] - mnew);
          mrun[a] = mnew;
#pragma unroll
          for (int n = 0; n < 4; ++n)
#pragma unroll
            for (int r = 0; r < 4; ++r) po[a][n][r] *= corr;
#pragma unroll
          for (int r = 0; r < 4; ++r) po_s[a][r] *= corr;
        }
#pragma unroll
        for (int sub = 0; sub < 4; ++sub) {
          bf16x4 pk;
#pragma unroll
          for (int r = 0; r < 4; ++r) pk[r] = (bf16_t)ex2(s[a][sub][r] - mrun[a]);
          *reinterpret_cast<bf16x4*>(&P[w][a * 16 + l15][sub * 16 + l4 * 4]) = pk;
        }
      }
#pragma unroll
      for (int a = 0; a < 2; ++a)
#pragma unroll
        for (int kk = 0; kk < 2; ++kk) {
          const bf16x8 pf =
              *reinterpret_cast<const bf16x8*>(&P[w][a * 16 + l15][kk * 32 + l4 * 8]);
          __builtin_amdgcn_s_setprio(1);
#pragma unroll
          for (int n = 0; n < 4; ++n) po[a][n] = mfma16(vf[kk][n], pf, po[a][n]);
          po_s[a] = mfma16(ones, pf, po_s[a]);
          __builtin_amdgcn_s_setprio(0);
        }
    }
    asm volatile("s_waitcnt vmcnt(0)" ::: "memory");
    __builtin_amdgcn_s_barrier();
    buf ^= 1;
  }

#pragma unroll
  for (int a = 0; a < 2; ++a) {
    const float inv = 1.f / po_s[a][0];
#pragma unroll
    for (int n = 0; n < 4; ++n) {
      bf16x4 ov;
#pragma unroll
      for (int r = 0; r < 4; ++r) ov[r] = (bf16_t)(po[a][n][r] * inv);
      __builtin_nontemporal_store(
          ov, reinterpret_cast<bf16x4*>(
                  O + (size_t)(b * kT + qr0 + a * 16 + l15) * kC + h * kHD + n * 16 + l4 * 4));
    }
  }
}

// ---------------- launcher ----------------
extern "C" void kernel_launch(void* const* d_in, const int* in_sizes, int n_in,
                              void* d_out, int out_size, void* d_ws, size_t ws_size,
                              hipStream_t stream) {
  const float* x      = (const float*)d_in[0];
  const float* enc    = (const float*)d_in[1];
  const float* sa_wq  = (const float*)d_in[2];
  const float* sa_wk  = (const float*)d_in[3];
  const float* sa_wv  = (const float*)d_in[4];
  const float* sa_pw  = (const float*)d_in[5];
  const float* sa_pb  = (const float*)d_in[6];
  const float* ca_wq  = (const float*)d_in[7];
  const float* ca_wk  = (const float*)d_in[8];
  const float* ca_wv  = (const float*)d_in[9];
  const float* ca_pw  = (const float*)d_in[10];
  const float* ca_pb  = (const float*)d_in[11];
  const float* ff_w1  = (const float*)d_in[12];
  const float* ff_b1  = (const float*)d_in[13];
  const float* ff_w2  = (const float*)d_in[14];
  const float* ff_b2  = (const float*)d_in[15];
  const float* ln1_g  = (const float*)d_in[16];
  const float* ln1_b  = (const float*)d_in[17];
  const float* ln2_g  = (const float*)d_in[18];
  const float* ln2_b  = (const float*)d_in[19];
  const float* ln3_g  = (const float*)d_in[20];
  const float* ln3_b  = (const float*)d_in[21];

  const size_t ACT_BF = (size_t)kM * kC * 2;   // 16 MiB
  const size_t ACT_F  = (size_t)kM * kC * 4;   // 32 MiB
  const size_t W_BF   = (size_t)kC * kC * 2;
  const size_t FF_BF  = (size_t)kC * kFF * 2;
  const size_t H_BF   = (size_t)kM * kFF * 2;

  char* ws = (char*)d_ws;
  size_t off = 0;
  auto alloc = [&](size_t bytes) {
    char* p = ws + off;
    off += (bytes + 255) & ~(size_t)255;
    return p;
  };
  bf16_t* xbf   = (bf16_t*)alloc(ACT_BF);
  bf16_t* encbf = (bf16_t*)alloc(ACT_BF);
  bf16_t* lnbuf = (bf16_t*)alloc(ACT_BF);
  bf16_t* wsaq  = (bf16_t*)alloc(W_BF);
  bf16_t* wkvsa = (bf16_t*)alloc(2 * W_BF);  // [2048][1024]: wk^T rows, then wv^T rows
  bf16_t* wsap  = (bf16_t*)alloc(W_BF);
  bf16_t* wcaq  = (bf16_t*)alloc(W_BF);
  bf16_t* wkvca = (bf16_t*)alloc(2 * W_BF);
  bf16_t* wcap  = (bf16_t*)alloc(W_BF);
  bf16_t* wff1t = (bf16_t*)alloc(FF_BF);   // [4096][1024]
  bf16_t* wff2t = (bf16_t*)alloc(FF_BF);   // [1024][4096]
  float*  rbuf  = (float*)alloc(ACT_F);    // residual chain (f32)
  char*   scr   = alloc(5 * ACT_BF > H_BF ? 5 * ACT_BF : H_BF);
  bf16_t* qbf   = (bf16_t*)scr;
  bf16_t* kbf   = (bf16_t*)(scr + ACT_BF);
  bf16_t* vtbf  = (bf16_t*)(scr + 3 * ACT_BF);
  bf16_t* aobf  = (bf16_t*)(scr + 4 * ACT_BF);
  bf16_t* hbf   = (bf16_t*)scr;            // FFN hidden reuses q..ao region

  const dim3 blk512(512), blk256(256), blkT(32, 8);
  const int n4 = kM * kC / 4;
  const dim3 gGemmC(kC / 128, kM / 128);       // (8, 64) = 512
  const dim3 gGemmKV(2 * kC / 128, kM / 128);  // (16, 64) = 1024
  const dim3 gGemmF(kFF / 128, kM / 128);      // (32, 64) = 2048
  const dim3 gAttn(kB, kH, kT / 256);          // (8, 16, 4) — 8 waves, 256 q-rows/block
  const uint32_t LDSB = 65536;                 // 64KB -> 2 blocks/CU

  hipFuncSetAttribute((const void*)k_gemm2<0, true>,  hipFuncAttributeMaxDynamicSharedMemorySize, LDSB);
  hipFuncSetAttribute((const void*)k_gemm2<1, true>,  hipFuncAttributeMaxDynamicSharedMemorySize, LDSB);
  hipFuncSetAttribute((const void*)k_gemm2<1, false>, hipFuncAttributeMaxDynamicSharedMemorySize, LDSB);
  hipFuncSetAttribute((const void*)k_gemm2<2, true>,  hipFuncAttributeMaxDynamicSharedMemorySize, LDSB);
  hipFuncSetAttribute((const void*)k_gemm2<4, true>,  hipFuncAttributeMaxDynamicSharedMemorySize, LDSB);

  // ---- input casts + weight transposes ----
  k_cast_bf16<<<n4 / 256, blk256, 0, stream>>>(enc, encbf, n4);
  Trans8Args ta;
  ta.src[0] = sa_wq; ta.dst[0] = wsaq;
  ta.src[1] = sa_wk; ta.dst[1] = wkvsa;
  ta.src[2] = sa_wv; ta.dst[2] = wkvsa + (size_t)kC * kC;
  ta.src[3] = sa_pw; ta.dst[3] = wsap;
  ta.src[4] = ca_wq; ta.dst[4] = wcaq;
  ta.src[5] = ca_wk; ta.dst[5] = wkvca;
  ta.src[6] = ca_wv; ta.dst[6] = wkvca + (size_t)kC * kC;
  ta.src[7] = ca_pw; ta.dst[7] = wcap;
  k_transpose_cast8<<<dim3(kC / 32, kC / 32, 8), blkT, 0, stream>>>(ta);
  k_transpose_cast<<<dim3(kFF / 32, kC / 32), blkT, 0, stream>>>(ff_w1, wff1t, kC, kFF);
  k_transpose_cast<<<dim3(kC / 32, kFF / 32), blkT, 0, stream>>>(ff_w2, wff2t, kFF, kC);

  // ---- self-attention (q from ln1(x), k/v from raw x, causal) ----
  k_ln<true><<<kM, blk256, 0, stream>>>(x, ln1_g, ln1_b, lnbuf, xbf);
  k_gemm2<0, true><<<gGemmC, blk256, LDSB, stream>>>(lnbuf, wsaq, nullptr, nullptr, nullptr, qbf, nullptr, kM, kC, kC);
  k_gemm2<4, true><<<gGemmKV, blk256, LDSB, stream>>>(xbf, wkvsa, nullptr, nullptr, nullptr, kbf, vtbf, kM, 2 * kC, kC);
  k_attn<true><<<gAttn, blk512, 0, stream>>>(qbf, kbf, vtbf, aobf);
  k_gemm2<1, true><<<gGemmC, blk256, LDSB, stream>>>(aobf, wsap, sa_pb, x, rbuf, nullptr, nullptr, kM, kC, kC);

  // ---- cross-attention (q from ln2(r), k/v from encoder_output) ----
  k_ln<false><<<kM, blk256, 0, stream>>>(rbuf, ln2_g, ln2_b, lnbuf, nullptr);
  k_gemm2<0, true><<<gGemmC, blk256, LDSB, stream>>>(lnbuf, wcaq, nullptr, nullptr, nullptr, qbf, nullptr, kM, kC, kC);
  k_gemm2<4, true><<<gGemmKV, blk256, LDSB, stream>>>(encbf, wkvca, nullptr, nullptr, nullptr, kbf, vtbf, kM, 2 * kC, kC);
  k_attn<false><<<gAttn, blk512, 0, stream>>>(qbf, kbf, vtbf, aobf);
  k_gemm2<1, true><<<gGemmC, blk256, LDSB, stream>>>(aobf, wcap, ca_pb, rbuf, rbuf, nullptr, nullptr, kM, kC, kC);

  // ---- feed-forward ----
  k_ln<false><<<kM, blk256, 0, stream>>>(rbuf, ln3_g, ln3_b, lnbuf, nullptr);
  k_gemm2<2, true><<<gGemmF, blk256, LDSB, stream>>>(lnbuf, wff1t, ff_b1, nullptr, nullptr, hbf, nullptr, kM, kFF, kC);
  k_gemm2<1, false><<<gGemmC, blk256, LDSB, stream>>>(hbf, wff2t, ff_b2, rbuf, (float*)d_out, nullptr, nullptr, kM, kC, kFF);

  (void)in_sizes; (void)n_in; (void)out_size; (void)ws_size;
}

// Round 18
// 477.729 us; speedup vs baseline: 1.0815x; 1.0815x over previous
//
#include <hip/hip_runtime.h>
#include <stdint.h>
#include <stddef.h>

typedef __bf16 bf16_t;
typedef __bf16 bf16x4 __attribute__((ext_vector_type(4)));
typedef __bf16 bf16x8 __attribute__((ext_vector_type(8)));
typedef float f32x4 __attribute__((ext_vector_type(4)));

#define DEV static __device__ __forceinline__

static constexpr int kB = 8, kT = 1024, kC = 1024, kM = 8192, kH = 16, kHD = 64, kFF = 4096;

DEV f32x4 mfma16(bf16x8 a, bf16x8 b, f32x4 c) {
  return __builtin_amdgcn_mfma_f32_16x16x32_bf16(a, b, c, 0, 0, 0);
}

// raw hardware exp2 (D = 2^S0); inputs always <= 0 here.
DEV float ex2(float x) {
  float r;
  asm("v_exp_f32 %0, %1" : "=v"(r) : "v"(x));
  return r;
}

// async global->LDS, 16B per lane. LDS dest must be wave-uniform base (+lane*16 by HW).
DEV void gload_lds16(const void* g, void* l) {
  __builtin_amdgcn_global_load_lds(
      reinterpret_cast<const __attribute__((address_space(1))) void*>(
          reinterpret_cast<uintptr_t>(g)),
      reinterpret_cast<__attribute__((address_space(3))) void*>(
          static_cast<uint32_t>(reinterpret_cast<uintptr_t>(l))),
      16, 0, 0);
}

// ---------------- cast f32 -> bf16 ----------------
__global__ void k_cast_bf16(const float* __restrict__ in, bf16_t* __restrict__ out, int n4) {
  int i = blockIdx.x * blockDim.x + threadIdx.x;
  if (i >= n4) return;
  float4 v = reinterpret_cast<const float4*>(in)[i];
  bf16x4 o;
  o[0] = (bf16_t)v.x; o[1] = (bf16_t)v.y; o[2] = (bf16_t)v.z; o[3] = (bf16_t)v.w;
  reinterpret_cast<bf16x4*>(out)[i] = o;
}

// ---------- batched transpose+cast: 8x f32[1024][1024] -> bf16[1024][1024]^T ----------
struct Trans8Args { const float* src[8]; bf16_t* dst[8]; };
__global__ void k_transpose_cast8(Trans8Args a) {
  __shared__ float tile[32][33];
  const float* __restrict__ in = a.src[blockIdx.z];
  bf16_t* __restrict__ out = a.dst[blockIdx.z];
  int c0 = blockIdx.x * 32, r0 = blockIdx.y * 32;
  int tx = threadIdx.x, ty = threadIdx.y;  // (32,8)
#pragma unroll
  for (int i = 0; i < 4; ++i)
    tile[ty + 8 * i][tx] = in[(size_t)(r0 + ty + 8 * i) * kC + c0 + tx];
  __syncthreads();
#pragma unroll
  for (int i = 0; i < 4; ++i)
    out[(size_t)(c0 + ty + 8 * i) * kC + r0 + tx] = (bf16_t)tile[tx][ty + 8 * i];
}

// ---------- transpose+cast f32[R][C] -> bf16[C][R] ----------
__global__ void k_transpose_cast(const float* __restrict__ in, bf16_t* __restrict__ out,
                                 int R, int C) {
  __shared__ float tile[32][33];
  int c0 = blockIdx.x * 32, r0 = blockIdx.y * 32;
  int tx = threadIdx.x, ty = threadIdx.y;  // (32,8)
#pragma unroll
  for (int i = 0; i < 4; ++i)
    tile[ty + 8 * i][tx] = in[(size_t)(r0 + ty + 8 * i) * C + c0 + tx];
  __syncthreads();
#pragma unroll
  for (int i = 0; i < 4; ++i)
    out[(size_t)(c0 + ty + 8 * i) * R + r0 + tx] = (bf16_t)tile[tx][ty + 8 * i];
}

// ---------------- layernorm f32 -> bf16 (one block per row of 1024) ----------------
template <bool CASTX>
__global__ __launch_bounds__(256) void k_ln(const float* __restrict__ in,
                                            const float* __restrict__ g,
                                            const float* __restrict__ b,
                                            bf16_t* __restrict__ out,
                                            bf16_t* __restrict__ rawout) {
  int row = blockIdx.x, t = threadIdx.x;
  const float4 v = reinterpret_cast<const float4*>(in + (size_t)row * kC)[t];
  if constexpr (CASTX) {
    bf16x4 c;
    c[0] = (bf16_t)v.x; c[1] = (bf16_t)v.y; c[2] = (bf16_t)v.z; c[3] = (bf16_t)v.w;
    reinterpret_cast<bf16x4*>(rawout + (size_t)row * kC)[t] = c;
  }
  float s = v.x + v.y + v.z + v.w;
  float ss = v.x * v.x + v.y * v.y + v.z * v.z + v.w * v.w;
#pragma unroll
  for (int off = 1; off < 64; off <<= 1) {
    s += __shfl_xor(s, off, 64);
    ss += __shfl_xor(ss, off, 64);
  }
  __shared__ float rs[4], rss[4];
  int w = t >> 6;
  if ((t & 63) == 0) { rs[w] = s; rss[w] = ss; }
  __syncthreads();
  s = rs[0] + rs[1] + rs[2] + rs[3];
  ss = rss[0] + rss[1] + rss[2] + rss[3];
  float mean = s * (1.f / kC);
  float var = ss * (1.f / kC) - mean * mean;
  float rstd = rsqrtf(var + 1e-5f);
  float4 gv = reinterpret_cast<const float4*>(g)[t];
  float4 bv = reinterpret_cast<const float4*>(b)[t];
  bf16x4 o;
  o[0] = (bf16_t)((v.x - mean) * rstd * gv.x + bv.x);
  o[1] = (bf16_t)((v.y - mean) * rstd * gv.y + bv.y);
  o[2] = (bf16_t)((v.z - mean) * rstd * gv.z + bv.z);
  o[3] = (bf16_t)((v.w - mean) * rstd * gv.w + bv.w);
  reinterpret_cast<bf16x4*>(out + (size_t)row * kC)[t] = o;
}

// ============ GEMM v4.2 (R16 proven): 128x128, 2 blocks/CU, XCD-chunked + in-band ====
// Plain stores (R17 lesson: nontemporal scalar bf16 stores bypass L2 write-combining ->
// 1.87x write amplification, WRITE 65.5->122MB, +7us. Reverted.)
// EPI: 0 = bf16 out; 1 = f32 out + bias + residual; 2 = bf16 out + bias + ReLU;
//      3 = bf16 transposed out (ld M); 4 = split KV
template <int EPI, bool YFAST>
__global__ __launch_bounds__(256, 2) void k_gemm2(
    const bf16_t* __restrict__ A, const bf16_t* __restrict__ Bt,
    const float* __restrict__ bias, const float* __restrict__ res,
    float* __restrict__ outf, bf16_t* __restrict__ outb, bf16_t* __restrict__ outb2,
    int M, int N, int K) {
  extern __shared__ bf16_t smem[];
  bf16_t* As = smem;                  // 2 x 128x64 (8192 el / buf)
  bf16_t* Bs = smem + 2 * 8192;       // 2 x 128x64
  const int t = threadIdx.x;
  const int w = t >> 6, lane = t & 63;
  const int l15 = lane & 15, l4 = lane >> 4;
  const int wr = w >> 1, wc = w & 1;

  // XCD-chunked bijective remap; in-band order per YFAST.
  const int gx = gridDim.x;
  const int nwg = gx * gridDim.y;
  const int lid = blockIdx.y * gx + blockIdx.x;
  const int band = lid & 7;
  const int tin = lid >> 3;
  int txi, tyi;
  if (YFAST) {
    txi = tin >> 3;
    tyi = band * 8 + (tin & 7);
  } else {
    const int tile = band * (nwg >> 3) + tin;
    txi = tile % gx;
    tyi = tile / gx;
  }
  const int bm0 = tyi * 128, bn0 = txi * 128;

  f32x4 acc[4][4] = {};

  const int srow = w * 8 + (lane >> 3);
  const int scol = ((lane & 7) ^ (lane >> 3)) * 8;
  const bf16_t* aSrc0 = A + (size_t)(bm0 + srow) * K + scol;
  const bf16_t* bSrc0 = Bt + (size_t)(bn0 + srow) * K + scol;
  const size_t r32 = (size_t)32 * K;

  const int arow = wr * 64 + l15;
  const int brow = wc * 64 + l15;
  const int cbx = (l15 & 7) * 16;
  const int cbe0 = ((l4 * 16) ^ cbx) >> 1;
  const int cbe1 = ((64 | (l4 * 16)) ^ cbx) >> 1;

  const int nkt = K >> 6;

  auto stage = [&](int tt, int bi) {
    const size_t ko = (size_t)tt * 64;
    bf16_t* da = As + bi * 8192 + w * 512;
    bf16_t* db = Bs + bi * 8192 + w * 512;
#pragma unroll
    for (int c = 0; c < 4; ++c) {
      gload_lds16(aSrc0 + ko + (size_t)c * r32, da + c * 2048);
      gload_lds16(bSrc0 + ko + (size_t)c * r32, db + c * 2048);
    }
  };

  stage(0, 0);
  asm volatile("s_waitcnt vmcnt(0)" ::: "memory");
  __builtin_amdgcn_s_barrier();

  int bi = 0;
  for (int tt = 0; tt < nkt; ++tt) {
    if (tt + 1 < nkt) stage(tt + 1, bi ^ 1);
    const bf16_t* bA = As + bi * 8192;
    const bf16_t* bB = Bs + bi * 8192;
    bf16x8 af[4], bfr[4];
#pragma unroll
    for (int m = 0; m < 4; ++m)
      af[m] = *reinterpret_cast<const bf16x8*>(&bA[(arow + m * 16) * 64 + cbe0]);
#pragma unroll
    for (int n = 0; n < 4; ++n)
      bfr[n] = *reinterpret_cast<const bf16x8*>(&bB[(brow + n * 16) * 64 + cbe0]);
    __builtin_amdgcn_s_setprio(1);
#pragma unroll
    for (int m = 0; m < 4; ++m)
#pragma unroll
      for (int n = 0; n < 4; ++n) acc[m][n] = mfma16(af[m], bfr[n], acc[m][n]);
    __builtin_amdgcn_s_setprio(0);
#pragma unroll
    for (int m = 0; m < 4; ++m)
      af[m] = *reinterpret_cast<const bf16x8*>(&bA[(arow + m * 16) * 64 + cbe1]);
#pragma unroll
    for (int n = 0; n < 4; ++n)
      bfr[n] = *reinterpret_cast<const bf16x8*>(&bB[(brow + n * 16) * 64 + cbe1]);
    __builtin_amdgcn_s_setprio(1);
#pragma unroll
    for (int m = 0; m < 4; ++m)
#pragma unroll
      for (int n = 0; n < 4; ++n) acc[m][n] = mfma16(af[m], bfr[n], acc[m][n]);
    __builtin_amdgcn_s_setprio(0);
    if (tt + 1 < nkt) {
      asm volatile("s_waitcnt vmcnt(0)" ::: "memory");
      __builtin_amdgcn_s_barrier();
    }
    bi ^= 1;
  }

  const int gm = bm0 + wr * 64 + l4 * 4;
  const int gn = bn0 + wc * 64 + l15;
  if constexpr (EPI == 0) {
#pragma unroll
    for (int m = 0; m < 4; ++m)
#pragma unroll
      for (int n = 0; n < 4; ++n)
#pragma unroll
        for (int r = 0; r < 4; ++r)
          outb[(size_t)(gm + m * 16 + r) * N + (gn + n * 16)] = (bf16_t)acc[m][n][r];
  } else if constexpr (EPI == 1) {
#pragma unroll
    for (int m = 0; m < 4; ++m)
#pragma unroll
      for (int n = 0; n < 4; ++n) {
        const int col = gn + n * 16;
        const float bv = bias[col];
#pragma unroll
        for (int r = 0; r < 4; ++r) {
          const size_t idx = (size_t)(gm + m * 16 + r) * N + col;
          outf[idx] = acc[m][n][r] + bv + res[idx];
        }
      }
  } else if constexpr (EPI == 2) {
#pragma unroll
    for (int m = 0; m < 4; ++m)
#pragma unroll
      for (int n = 0; n < 4; ++n) {
        const int col = gn + n * 16;
        const float bv = bias[col];
#pragma unroll
        for (int r = 0; r < 4; ++r) {
          float v = acc[m][n][r] + bv;
          v = fmaxf(v, 0.f);
          outb[(size_t)(gm + m * 16 + r) * N + col] = (bf16_t)v;
        }
      }
  } else if constexpr (EPI == 3) {
#pragma unroll
    for (int m = 0; m < 4; ++m)
#pragma unroll
      for (int n = 0; n < 4; ++n) {
        bf16x4 ov;
#pragma unroll
        for (int r = 0; r < 4; ++r) ov[r] = (bf16_t)acc[m][n][r];
        *reinterpret_cast<bf16x4*>(&outb[(size_t)(gn + n * 16) * M + gm + m * 16]) = ov;
      }
  } else {  // EPI == 4: split KV (block-uniform: bn0 multiple of 128)
    const int half = N >> 1;
    if (bn0 < half) {
#pragma unroll
      for (int m = 0; m < 4; ++m)
#pragma unroll
        for (int n = 0; n < 4; ++n)
#pragma unroll
          for (int r = 0; r < 4; ++r)
            outb[(size_t)(gm + m * 16 + r) * half + (gn + n * 16)] = (bf16_t)acc[m][n][r];
    } else {
#pragma unroll
      for (int m = 0; m < 4; ++m)
#pragma unroll
        for (int n = 0; n < 4; ++n) {
          bf16x4 ov;
#pragma unroll
          for (int r = 0; r < 4; ++r) ov[r] = (bf16_t)acc[m][n][r];
          *reinterpret_cast<bf16x4*>(
              &outb2[(size_t)(gn + n * 16 - half) * M + gm + m * 16]) = ov;
        }
    }
  }
}

// ---------------- flash attention v3: 512-thread blocks, 256 q-rows ----------------
// Grid (b, h, qseg): 8 waves, wave w owns q-rows qseg*256 + w*32. K/V staged once per
// 256 q-rows (2 gloads/wave/tile); LDS 68KB -> 2 blocks/CU x 8 waves = 16 waves/CU.
// CAUSAL: qseg reversed (longest-first); per-wave gating at klim. Plain O stores.
template <bool CAUSAL>
__global__ __launch_bounds__(512) void k_attn(const bf16_t* __restrict__ Q,
                                              const bf16_t* __restrict__ Kb,
                                              const bf16_t* __restrict__ Vt,
                                              bf16_t* __restrict__ O) {
  __shared__ bf16_t Ks[2][4096];   // [buf][64 key-rows][64 d-el], swizzled rows
  __shared__ bf16_t Vs[2][4096];   // [buf][64 d-rows][64 key-el], swizzled rows
  __shared__ bf16_t P[8][32][72];  // per-wave P buffer
  const int b = blockIdx.x, h = blockIdx.y;
  const int w = threadIdx.x >> 6, lane = threadIdx.x & 63;
  const int l15 = lane & 15, l4 = lane >> 4;
  const int qseg = CAUSAL ? (kT / 256 - 1 - blockIdx.z) : blockIdx.z;
  const int qr0 = qseg * 256 + w * 32;  // this wave's first q-row

  bf16x8 qf[2][2];
#pragma unroll
  for (int a = 0; a < 2; ++a) {
    const bf16_t* qp = Q + (size_t)(b * kT + qr0 + a * 16 + l15) * kC + h * kHD + l4 * 8;
    qf[a][0] = *reinterpret_cast<const bf16x8*>(qp);
    qf[a][1] = *reinterpret_cast<const bf16x8*>(qp + 32);
#pragma unroll
    for (int j = 0; j < 8; ++j) {
      qf[a][0][j] = (bf16_t)((float)qf[a][0][j] * 0.1803368801111204f);
      qf[a][1][j] = (bf16_t)((float)qf[a][1][j] * 0.1803368801111204f);
    }
  }
  bf16x8 ones;
#pragma unroll
  for (int j = 0; j < 8; ++j) ones[j] = (bf16_t)1.0f;

  f32x4 po[2][4] = {};
  f32x4 po_s[2] = {};
  float mrun[2];
  mrun[0] = mrun[1] = -3.0e38f;

  const int nkt = CAUSAL ? 4 * qseg + 4 : (kT / 64);
  const int klim = CAUSAL ? ((qr0 + 31) >> 6) : (1 << 30);

  const int lr = lane >> 3;
  const int cswz = ((lane & 7) ^ lr) * 8;
  const bf16_t* kSrc = Kb + (size_t)(b * kT + w * 8 + lr) * kC + h * kHD + cswz;
  const bf16_t* vSrc = Vt + (size_t)(h * kHD + w * 8 + lr) * (kB * kT) + b * kT + cswz;

  auto stage = [&](int kt, int buf) {
    gload_lds16(kSrc + (size_t)kt * 64 * kC, &Ks[buf][w * 512]);
    gload_lds16(vSrc + (size_t)kt * 64,      &Vs[buf][w * 512]);
  };

  const int cbx = (l15 & 7) * 16;
  const int rb0 = ((l4 * 16) ^ cbx) >> 1;
  const int rb1 = ((64 | (l4 * 16)) ^ cbx) >> 1;

  stage(0, 0);
  asm volatile("s_waitcnt vmcnt(0)" ::: "memory");
  __builtin_amdgcn_s_barrier();

  int buf = 0;
  for (int kt = 0; kt < nkt; ++kt) {
    if (kt + 1 < nkt) stage(kt + 1, buf ^ 1);
    if (kt <= klim) {
      bf16x8 kf[4][2];
#pragma unroll
      for (int sub = 0; sub < 4; ++sub) {
        kf[sub][0] = *reinterpret_cast<const bf16x8*>(&Ks[buf][(sub * 16 + l15) * 64 + rb0]);
        kf[sub][1] = *reinterpret_cast<const bf16x8*>(&Ks[buf][(sub * 16 + l15) * 64 + rb1]);
      }
      bf16x8 vf[2][4];
#pragma unroll
      for (int n = 0; n < 4; ++n) {
        vf[0][n] = *reinterpret_cast<const bf16x8*>(&Vs[buf][(n * 16 + l15) * 64 + rb0]);
        vf[1][n] = *reinterpret_cast<const bf16x8*>(&Vs[buf][(n * 16 + l15) * 64 + rb1]);
      }

      f32x4 s[2][4] = {};
      __builtin_amdgcn_s_setprio(1);
#pragma unroll
      for (int a = 0; a < 2; ++a)
#pragma unroll
        for (int sub = 0; sub < 4; ++sub) {
          s[a][sub] = mfma16(kf[sub][0], qf[a][0], s[a][sub]);
          s[a][sub] = mfma16(kf[sub][1], qf[a][1], s[a][sub]);
        }
      __builtin_amdgcn_s_setprio(0);
      if (CAUSAL && kt == klim) {
#pragma unroll
        for (int a = 0; a < 2; ++a) {
          const int qrow = qr0 + a * 16 + l15;
#pragma unroll
          for (int sub = 0; sub < 4; ++sub)
#pragma unroll
            for (int r = 0; r < 4; ++r) {
              const int key = kt * 64 + sub * 16 + l4 * 4 + r;
              if (key > qrow) s[a][sub][r] = -3.0e38f;
            }
        }
      }
#pragma unroll
      for (int a = 0; a < 2; ++a) {
        float t0 = fmaxf(fmaxf(s[a][0][0], s[a][0][1]), fmaxf(s[a][0][2], s[a][0][3]));
        float t1 = fmaxf(fmaxf(s[a][1][0], s[a][1][1]), fmaxf(s[a][1][2], s[a][1][3]));
        float t2 = fmaxf(fmaxf(s[a][2][0], s[a][2][1]), fmaxf(s[a][2][2], s[a][2][3]));
        float t3 = fmaxf(fmaxf(s[a][3][0], s[a][3][1]), fmaxf(s[a][3][2], s[a][3][3]));
        float v = fmaxf(fmaxf(t0, t1), fmaxf(t2, t3));
        v = fmaxf(v, __shfl_xor(v, 16, 64));
        v = fmaxf(v, __shfl_xor(v, 32, 64));
        if (!__all(v <= mrun[a] + 8.f)) {
          const float mnew = fmaxf(mrun[a], v);
          const float corr = ex2(mrun[a] - mnew);
          mrun[a] = mnew;
#pragma unroll
          for (int n = 0; n < 4; ++n)
#pragma unroll
            for (int r = 0; r < 4; ++r) po[a][n][r] *= corr;
#pragma unroll
          for (int r = 0; r < 4; ++r) po_s[a][r] *= corr;
        }
#pragma unroll
        for (int sub = 0; sub < 4; ++sub) {
          bf16x4 pk;
#pragma unroll
          for (int r = 0; r < 4; ++r) pk[r] = (bf16_t)ex2(s[a][sub][r] - mrun[a]);
          *reinterpret_cast<bf16x4*>(&P[w][a * 16 + l15][sub * 16 + l4 * 4]) = pk;
        }
      }
#pragma unroll
      for (int a = 0; a < 2; ++a)
#pragma unroll
        for (int kk = 0; kk < 2; ++kk) {
          const bf16x8 pf =
              *reinterpret_cast<const bf16x8*>(&P[w][a * 16 + l15][kk * 32 + l4 * 8]);
          __builtin_amdgcn_s_setprio(1);
#pragma unroll
          for (int n = 0; n < 4; ++n) po[a][n] = mfma16(vf[kk][n], pf, po[a][n]);
          po_s[a] = mfma16(ones, pf, po_s[a]);
          __builtin_amdgcn_s_setprio(0);
        }
    }
    asm volatile("s_waitcnt vmcnt(0)" ::: "memory");
    __builtin_amdgcn_s_barrier();
    buf ^= 1;
  }

#pragma unroll
  for (int a = 0; a < 2; ++a) {
    const float inv = 1.f / po_s[a][0];
#pragma unroll
    for (int n = 0; n < 4; ++n) {
      bf16x4 ov;
#pragma unroll
      for (int r = 0; r < 4; ++r) ov[r] = (bf16_t)(po[a][n][r] * inv);
      *reinterpret_cast<bf16x4*>(
          O + (size_t)(b * kT + qr0 + a * 16 + l15) * kC + h * kHD + n * 16 + l4 * 4) = ov;
    }
  }
}

// ---------------- launcher ----------------
extern "C" void kernel_launch(void* const* d_in, const int* in_sizes, int n_in,
                              void* d_out, int out_size, void* d_ws, size_t ws_size,
                              hipStream_t stream) {
  const float* x      = (const float*)d_in[0];
  const float* enc    = (const float*)d_in[1];
  const float* sa_wq  = (const float*)d_in[2];
  const float* sa_wk  = (const float*)d_in[3];
  const float* sa_wv  = (const float*)d_in[4];
  const float* sa_pw  = (const float*)d_in[5];
  const float* sa_pb  = (const float*)d_in[6];
  const float* ca_wq  = (const float*)d_in[7];
  const float* ca_wk  = (const float*)d_in[8];
  const float* ca_wv  = (const float*)d_in[9];
  const float* ca_pw  = (const float*)d_in[10];
  const float* ca_pb  = (const float*)d_in[11];
  const float* ff_w1  = (const float*)d_in[12];
  const float* ff_b1  = (const float*)d_in[13];
  const float* ff_w2  = (const float*)d_in[14];
  const float* ff_b2  = (const float*)d_in[15];
  const float* ln1_g  = (const float*)d_in[16];
  const float* ln1_b  = (const float*)d_in[17];
  const float* ln2_g  = (const float*)d_in[18];
  const float* ln2_b  = (const float*)d_in[19];
  const float* ln3_g  = (const float*)d_in[20];
  const float* ln3_b  = (const float*)d_in[21];

  const size_t ACT_BF = (size_t)kM * kC * 2;   // 16 MiB
  const size_t ACT_F  = (size_t)kM * kC * 4;   // 32 MiB
  const size_t W_BF   = (size_t)kC * kC * 2;
  const size_t FF_BF  = (size_t)kC * kFF * 2;
  const size_t H_BF   = (size_t)kM * kFF * 2;

  char* ws = (char*)d_ws;
  size_t off = 0;
  auto alloc = [&](size_t bytes) {
    char* p = ws + off;
    off += (bytes + 255) & ~(size_t)255;
    return p;
  };
  bf16_t* xbf   = (bf16_t*)alloc(ACT_BF);
  bf16_t* encbf = (bf16_t*)alloc(ACT_BF);
  bf16_t* lnbuf = (bf16_t*)alloc(ACT_BF);
  bf16_t* wsaq  = (bf16_t*)alloc(W_BF);
  bf16_t* wkvsa = (bf16_t*)alloc(2 * W_BF);  // [2048][1024]: wk^T rows, then wv^T rows
  bf16_t* wsap  = (bf16_t*)alloc(W_BF);
  bf16_t* wcaq  = (bf16_t*)alloc(W_BF);
  bf16_t* wkvca = (bf16_t*)alloc(2 * W_BF);
  bf16_t* wcap  = (bf16_t*)alloc(W_BF);
  bf16_t* wff1t = (bf16_t*)alloc(FF_BF);   // [4096][1024]
  bf16_t* wff2t = (bf16_t*)alloc(FF_BF);   // [1024][4096]
  float*  rbuf  = (float*)alloc(ACT_F);    // residual chain (f32)
  char*   scr   = alloc(5 * ACT_BF > H_BF ? 5 * ACT_BF : H_BF);
  bf16_t* qbf   = (bf16_t*)scr;
  bf16_t* kbf   = (bf16_t*)(scr + ACT_BF);
  bf16_t* vtbf  = (bf16_t*)(scr + 3 * ACT_BF);
  bf16_t* aobf  = (bf16_t*)(scr + 4 * ACT_BF);
  bf16_t* hbf   = (bf16_t*)scr;            // FFN hidden reuses q..ao region

  const dim3 blk512(512), blk256(256), blkT(32, 8);
  const int n4 = kM * kC / 4;
  const dim3 gGemmC(kC / 128, kM / 128);       // (8, 64) = 512
  const dim3 gGemmKV(2 * kC / 128, kM / 128);  // (16, 64) = 1024
  const dim3 gGemmF(kFF / 128, kM / 128);      // (32, 64) = 2048
  const dim3 gAttn(kB, kH, kT / 256);          // (8, 16, 4) — 8 waves, 256 q-rows/block
  const uint32_t LDSB = 65536;                 // 64KB -> 2 blocks/CU

  hipFuncSetAttribute((const void*)k_gemm2<0, true>,  hipFuncAttributeMaxDynamicSharedMemorySize, LDSB);
  hipFuncSetAttribute((const void*)k_gemm2<1, true>,  hipFuncAttributeMaxDynamicSharedMemorySize, LDSB);
  hipFuncSetAttribute((const void*)k_gemm2<1, false>, hipFuncAttributeMaxDynamicSharedMemorySize, LDSB);
  hipFuncSetAttribute((const void*)k_gemm2<2, true>,  hipFuncAttributeMaxDynamicSharedMemorySize, LDSB);
  hipFuncSetAttribute((const void*)k_gemm2<4, true>,  hipFuncAttributeMaxDynamicSharedMemorySize, LDSB);

  // ---- input casts + weight transposes ----
  k_cast_bf16<<<n4 / 256, blk256, 0, stream>>>(enc, encbf, n4);
  Trans8Args ta;
  ta.src[0] = sa_wq; ta.dst[0] = wsaq;
  ta.src[1] = sa_wk; ta.dst[1] = wkvsa;
  ta.src[2] = sa_wv; ta.dst[2] = wkvsa + (size_t)kC * kC;
  ta.src[3] = sa_pw; ta.dst[3] = wsap;
  ta.src[4] = ca_wq; ta.dst[4] = wcaq;
  ta.src[5] = ca_wk; ta.dst[5] = wkvca;
  ta.src[6] = ca_wv; ta.dst[6] = wkvca + (size_t)kC * kC;
  ta.src[7] = ca_pw; ta.dst[7] = wcap;
  k_transpose_cast8<<<dim3(kC / 32, kC / 32, 8), blkT, 0, stream>>>(ta);
  k_transpose_cast<<<dim3(kFF / 32, kC / 32), blkT, 0, stream>>>(ff_w1, wff1t, kC, kFF);
  k_transpose_cast<<<dim3(kC / 32, kFF / 32), blkT, 0, stream>>>(ff_w2, wff2t, kFF, kC);

  // ---- self-attention (q from ln1(x), k/v from raw x, causal) ----
  k_ln<true><<<kM, blk256, 0, stream>>>(x, ln1_g, ln1_b, lnbuf, xbf);
  k_gemm2<0, true><<<gGemmC, blk256, LDSB, stream>>>(lnbuf, wsaq, nullptr, nullptr, nullptr, qbf, nullptr, kM, kC, kC);
  k_gemm2<4, true><<<gGemmKV, blk256, LDSB, stream>>>(xbf, wkvsa, nullptr, nullptr, nullptr, kbf, vtbf, kM, 2 * kC, kC);
  k_attn<true><<<gAttn, blk512, 0, stream>>>(qbf, kbf, vtbf, aobf);
  k_gemm2<1, true><<<gGemmC, blk256, LDSB, stream>>>(aobf, wsap, sa_pb, x, rbuf, nullptr, nullptr, kM, kC, kC);

  // ---- cross-attention (q from ln2(r), k/v from encoder_output) ----
  k_ln<false><<<kM, blk256, 0, stream>>>(rbuf, ln2_g, ln2_b, lnbuf, nullptr);
  k_gemm2<0, true><<<gGemmC, blk256, LDSB, stream>>>(lnbuf, wcaq, nullptr, nullptr, nullptr, qbf, nullptr, kM, kC, kC);
  k_gemm2<4, true><<<gGemmKV, blk256, LDSB, stream>>>(encbf, wkvca, nullptr, nullptr, nullptr, kbf, vtbf, kM, 2 * kC, kC);
  k_attn<false><<<gAttn, blk512, 0, stream>>>(qbf, kbf, vtbf, aobf);
  k_gemm2<1, true><<<gGemmC, blk256, LDSB, stream>>>(aobf, wcap, ca_pb, rbuf, rbuf, nullptr, nullptr, kM, kC, kC);

  // ---- feed-forward ----
  k_ln<false><<<kM, blk256, 0, stream>>>(rbuf, ln3_g, ln3_b, lnbuf, nullptr);
  k_gemm2<2, true><<<gGemmF, blk256, LDSB, stream>>>(lnbuf, wff1t, ff_b1, nullptr, nullptr, hbf, nullptr, kM, kFF, kC);
  k_gemm2<1, false><<<gGemmC, blk256, LDSB, stream>>>(hbf, wff2t, ff_b2, rbuf, (float*)d_out, nullptr, nullptr, kM, kC, kFF);

  (void)in_sizes; (void)n_in; (void)out_size; (void)ws_size;
}

// Round 19
// 471.530 us; speedup vs baseline: 1.0957x; 1.0131x over previous
//
#include <hip/hip_runtime.h>
#include <stdint.h>
#include <stddef.h>

typedef __bf16 bf16_t;
typedef __bf16 bf16x4 __attribute__((ext_vector_type(4)));
typedef __bf16 bf16x8 __attribute__((ext_vector_type(8)));
typedef float f32x4 __attribute__((ext_vector_type(4)));

#define DEV static __device__ __forceinline__

static constexpr int kB = 8, kT = 1024, kC = 1024, kM = 8192, kH = 16, kHD = 64, kFF = 4096;

DEV f32x4 mfma16(bf16x8 a, bf16x8 b, f32x4 c) {
  return __builtin_amdgcn_mfma_f32_16x16x32_bf16(a, b, c, 0, 0, 0);
}

// raw hardware exp2 (D = 2^S0); inputs always <= 0 here.
DEV float ex2(float x) {
  float r;
  asm("v_exp_f32 %0, %1" : "=v"(r) : "v"(x));
  return r;
}

// async global->LDS, 16B per lane. LDS dest must be wave-uniform base (+lane*16 by HW).
DEV void gload_lds16(const void* g, void* l) {
  __builtin_amdgcn_global_load_lds(
      reinterpret_cast<const __attribute__((address_space(1))) void*>(
          reinterpret_cast<uintptr_t>(g)),
      reinterpret_cast<__attribute__((address_space(3))) void*>(
          static_cast<uint32_t>(reinterpret_cast<uintptr_t>(l))),
      16, 0, 0);
}

// ---------------- cast f32 -> bf16 ----------------
__global__ void k_cast_bf16(const float* __restrict__ in, bf16_t* __restrict__ out, int n4) {
  int i = blockIdx.x * blockDim.x + threadIdx.x;
  if (i >= n4) return;
  float4 v = reinterpret_cast<const float4*>(in)[i];
  bf16x4 o;
  o[0] = (bf16_t)v.x; o[1] = (bf16_t)v.y; o[2] = (bf16_t)v.z; o[3] = (bf16_t)v.w;
  reinterpret_cast<bf16x4*>(out)[i] = o;
}

// ---------- batched transpose+cast: 8x f32[1024][1024] -> bf16[1024][1024]^T ----------
struct Trans8Args { const float* src[8]; bf16_t* dst[8]; };
__global__ void k_transpose_cast8(Trans8Args a) {
  __shared__ float tile[32][33];
  const float* __restrict__ in = a.src[blockIdx.z];
  bf16_t* __restrict__ out = a.dst[blockIdx.z];
  int c0 = blockIdx.x * 32, r0 = blockIdx.y * 32;
  int tx = threadIdx.x, ty = threadIdx.y;  // (32,8)
#pragma unroll
  for (int i = 0; i < 4; ++i)
    tile[ty + 8 * i][tx] = in[(size_t)(r0 + ty + 8 * i) * kC + c0 + tx];
  __syncthreads();
#pragma unroll
  for (int i = 0; i < 4; ++i)
    out[(size_t)(c0 + ty + 8 * i) * kC + r0 + tx] = (bf16_t)tile[tx][ty + 8 * i];
}

// ---------- transpose+cast f32[R][C] -> bf16[C][R] ----------
__global__ void k_transpose_cast(const float* __restrict__ in, bf16_t* __restrict__ out,
                                 int R, int C) {
  __shared__ float tile[32][33];
  int c0 = blockIdx.x * 32, r0 = blockIdx.y * 32;
  int tx = threadIdx.x, ty = threadIdx.y;  // (32,8)
#pragma unroll
  for (int i = 0; i < 4; ++i)
    tile[ty + 8 * i][tx] = in[(size_t)(r0 + ty + 8 * i) * C + c0 + tx];
  __syncthreads();
#pragma unroll
  for (int i = 0; i < 4; ++i)
    out[(size_t)(c0 + ty + 8 * i) * R + r0 + tx] = (bf16_t)tile[tx][ty + 8 * i];
}

// ---------------- layernorm f32 -> bf16 (one block per row of 1024) ----------------
template <bool CASTX>
__global__ __launch_bounds__(256) void k_ln(const float* __restrict__ in,
                                            const float* __restrict__ g,
                                            const float* __restrict__ b,
                                            bf16_t* __restrict__ out,
                                            bf16_t* __restrict__ rawout) {
  int row = blockIdx.x, t = threadIdx.x;
  const float4 v = reinterpret_cast<const float4*>(in + (size_t)row * kC)[t];
  if constexpr (CASTX) {
    bf16x4 c;
    c[0] = (bf16_t)v.x; c[1] = (bf16_t)v.y; c[2] = (bf16_t)v.z; c[3] = (bf16_t)v.w;
    reinterpret_cast<bf16x4*>(rawout + (size_t)row * kC)[t] = c;
  }
  float s = v.x + v.y + v.z + v.w;
  float ss = v.x * v.x + v.y * v.y + v.z * v.z + v.w * v.w;
#pragma unroll
  for (int off = 1; off < 64; off <<= 1) {
    s += __shfl_xor(s, off, 64);
    ss += __shfl_xor(ss, off, 64);
  }
  __shared__ float rs[4], rss[4];
  int w = t >> 6;
  if ((t & 63) == 0) { rs[w] = s; rss[w] = ss; }
  __syncthreads();
  s = rs[0] + rs[1] + rs[2] + rs[3];
  ss = rss[0] + rss[1] + rss[2] + rss[3];
  float mean = s * (1.f / kC);
  float var = ss * (1.f / kC) - mean * mean;
  float rstd = rsqrtf(var + 1e-5f);
  float4 gv = reinterpret_cast<const float4*>(g)[t];
  float4 bv = reinterpret_cast<const float4*>(b)[t];
  bf16x4 o;
  o[0] = (bf16_t)((v.x - mean) * rstd * gv.x + bv.x);
  o[1] = (bf16_t)((v.y - mean) * rstd * gv.y + bv.y);
  o[2] = (bf16_t)((v.z - mean) * rstd * gv.z + bv.z);
  o[3] = (bf16_t)((v.w - mean) * rstd * gv.w + bv.w);
  reinterpret_cast<bf16x4*>(out + (size_t)row * kC)[t] = o;
}

// ============ GEMM v4.4: 128x128, 2 blocks/CU, XCD-chunked + in-band order ============
// As R18 (proven) + staging addresses as pre-incremented running pointers (staged-tile
// index is monotone +1) — removes per-tile 64-bit address recompute (VALU trim; m97-asm
// evidence: 21 v_lshl_add_u64 per loop for exactly this pattern).
// EPI: 0 = bf16 out; 1 = f32 out + bias + residual; 2 = bf16 out + bias + ReLU;
//      3 = bf16 transposed out (ld M); 4 = split KV
template <int EPI, bool YFAST>
__global__ __launch_bounds__(256, 2) void k_gemm2(
    const bf16_t* __restrict__ A, const bf16_t* __restrict__ Bt,
    const float* __restrict__ bias, const float* __restrict__ res,
    float* __restrict__ outf, bf16_t* __restrict__ outb, bf16_t* __restrict__ outb2,
    int M, int N, int K) {
  extern __shared__ bf16_t smem[];
  bf16_t* As = smem;                  // 2 x 128x64 (8192 el / buf)
  bf16_t* Bs = smem + 2 * 8192;       // 2 x 128x64
  const int t = threadIdx.x;
  const int w = t >> 6, lane = t & 63;
  const int l15 = lane & 15, l4 = lane >> 4;
  const int wr = w >> 1, wc = w & 1;

  // XCD-chunked bijective remap; in-band order per YFAST.
  const int gx = gridDim.x;
  const int nwg = gx * gridDim.y;
  const int lid = blockIdx.y * gx + blockIdx.x;
  const int band = lid & 7;
  const int tin = lid >> 3;
  int txi, tyi;
  if (YFAST) {
    txi = tin >> 3;
    tyi = band * 8 + (tin & 7);
  } else {
    const int tile = band * (nwg >> 3) + tin;
    txi = tile % gx;
    tyi = tile / gx;
  }
  const int bm0 = tyi * 128, bn0 = txi * 128;

  f32x4 acc[4][4] = {};

  const int srow = w * 8 + (lane >> 3);
  const int scol = ((lane & 7) ^ (lane >> 3)) * 8;
  const size_t r32 = (size_t)32 * K;
  // running staging pointers: staged tile index advances by exactly 1 per stage call
  const bf16_t* aStage = A + (size_t)(bm0 + srow) * K + scol;
  const bf16_t* bStage = Bt + (size_t)(bn0 + srow) * K + scol;

  const int arow = wr * 64 + l15;
  const int brow = wc * 64 + l15;
  const int cbx = (l15 & 7) * 16;
  const int cbe0 = ((l4 * 16) ^ cbx) >> 1;
  const int cbe1 = ((64 | (l4 * 16)) ^ cbx) >> 1;

  const int nkt = K >> 6;

  auto stage = [&](int bi) {  // stages the tile at the current running pointers, then advances
    bf16_t* da = As + bi * 8192 + w * 512;
    bf16_t* db = Bs + bi * 8192 + w * 512;
#pragma unroll
    for (int c = 0; c < 4; ++c) {
      gload_lds16(aStage + (size_t)c * r32, da + c * 2048);
      gload_lds16(bStage + (size_t)c * r32, db + c * 2048);
    }
    aStage += 64;
    bStage += 64;
  };

  stage(0);
  asm volatile("s_waitcnt vmcnt(0)" ::: "memory");
  __builtin_amdgcn_s_barrier();

  int bi = 0;
  for (int tt = 0; tt < nkt; ++tt) {
    if (tt + 1 < nkt) stage(bi ^ 1);
    const bf16_t* bA = As + bi * 8192;
    const bf16_t* bB = Bs + bi * 8192;
    bf16x8 af[4], bfr[4];
#pragma unroll
    for (int m = 0; m < 4; ++m)
      af[m] = *reinterpret_cast<const bf16x8*>(&bA[(arow + m * 16) * 64 + cbe0]);
#pragma unroll
    for (int n = 0; n < 4; ++n)
      bfr[n] = *reinterpret_cast<const bf16x8*>(&bB[(brow + n * 16) * 64 + cbe0]);
    __builtin_amdgcn_s_setprio(1);
#pragma unroll
    for (int m = 0; m < 4; ++m)
#pragma unroll
      for (int n = 0; n < 4; ++n) acc[m][n] = mfma16(af[m], bfr[n], acc[m][n]);
    __builtin_amdgcn_s_setprio(0);
#pragma unroll
    for (int m = 0; m < 4; ++m)
      af[m] = *reinterpret_cast<const bf16x8*>(&bA[(arow + m * 16) * 64 + cbe1]);
#pragma unroll
    for (int n = 0; n < 4; ++n)
      bfr[n] = *reinterpret_cast<const bf16x8*>(&bB[(brow + n * 16) * 64 + cbe1]);
    __builtin_amdgcn_s_setprio(1);
#pragma unroll
    for (int m = 0; m < 4; ++m)
#pragma unroll
      for (int n = 0; n < 4; ++n) acc[m][n] = mfma16(af[m], bfr[n], acc[m][n]);
    __builtin_amdgcn_s_setprio(0);
    if (tt + 1 < nkt) {
      asm volatile("s_waitcnt vmcnt(0)" ::: "memory");
      __builtin_amdgcn_s_barrier();
    }
    bi ^= 1;
  }

  const int gm = bm0 + wr * 64 + l4 * 4;
  const int gn = bn0 + wc * 64 + l15;
  if constexpr (EPI == 0) {
#pragma unroll
    for (int m = 0; m < 4; ++m)
#pragma unroll
      for (int n = 0; n < 4; ++n)
#pragma unroll
        for (int r = 0; r < 4; ++r)
          outb[(size_t)(gm + m * 16 + r) * N + (gn + n * 16)] = (bf16_t)acc[m][n][r];
  } else if constexpr (EPI == 1) {
#pragma unroll
    for (int m = 0; m < 4; ++m)
#pragma unroll
      for (int n = 0; n < 4; ++n) {
        const int col = gn + n * 16;
        const float bv = bias[col];
#pragma unroll
        for (int r = 0; r < 4; ++r) {
          const size_t idx = (size_t)(gm + m * 16 + r) * N + col;
          outf[idx] = acc[m][n][r] + bv + res[idx];
        }
      }
  } else if constexpr (EPI == 2) {
#pragma unroll
    for (int m = 0; m < 4; ++m)
#pragma unroll
      for (int n = 0; n < 4; ++n) {
        const int col = gn + n * 16;
        const float bv = bias[col];
#pragma unroll
        for (int r = 0; r < 4; ++r) {
          float v = acc[m][n][r] + bv;
          v = fmaxf(v, 0.f);
          outb[(size_t)(gm + m * 16 + r) * N + col] = (bf16_t)v;
        }
      }
  } else if constexpr (EPI == 3) {
#pragma unroll
    for (int m = 0; m < 4; ++m)
#pragma unroll
      for (int n = 0; n < 4; ++n) {
        bf16x4 ov;
#pragma unroll
        for (int r = 0; r < 4; ++r) ov[r] = (bf16_t)acc[m][n][r];
        *reinterpret_cast<bf16x4*>(&outb[(size_t)(gn + n * 16) * M + gm + m * 16]) = ov;
      }
  } else {  // EPI == 4: split KV (block-uniform: bn0 multiple of 128)
    const int half = N >> 1;
    if (bn0 < half) {
#pragma unroll
      for (int m = 0; m < 4; ++m)
#pragma unroll
        for (int n = 0; n < 4; ++n)
#pragma unroll
          for (int r = 0; r < 4; ++r)
            outb[(size_t)(gm + m * 16 + r) * half + (gn + n * 16)] = (bf16_t)acc[m][n][r];
    } else {
#pragma unroll
      for (int m = 0; m < 4; ++m)
#pragma unroll
        for (int n = 0; n < 4; ++n) {
          bf16x4 ov;
#pragma unroll
          for (int r = 0; r < 4; ++r) ov[r] = (bf16_t)acc[m][n][r];
          *reinterpret_cast<bf16x4*>(
              &outb2[(size_t)(gn + n * 16 - half) * M + gm + m * 16]) = ov;
        }
    }
  }
}

// ---------------- flash attention v3.1: 512-thread blocks, 256 q-rows ----------------
// As R18 (proven) + running staging pointers (staged kt advances monotonically).
template <bool CAUSAL>
__global__ __launch_bounds__(512) void k_attn(const bf16_t* __restrict__ Q,
                                              const bf16_t* __restrict__ Kb,
                                              const bf16_t* __restrict__ Vt,
                                              bf16_t* __restrict__ O) {
  __shared__ bf16_t Ks[2][4096];   // [buf][64 key-rows][64 d-el], swizzled rows
  __shared__ bf16_t Vs[2][4096];   // [buf][64 d-rows][64 key-el], swizzled rows
  __shared__ bf16_t P[8][32][72];  // per-wave P buffer
  const int b = blockIdx.x, h = blockIdx.y;
  const int w = threadIdx.x >> 6, lane = threadIdx.x & 63;
  const int l15 = lane & 15, l4 = lane >> 4;
  const int qseg = CAUSAL ? (kT / 256 - 1 - blockIdx.z) : blockIdx.z;
  const int qr0 = qseg * 256 + w * 32;  // this wave's first q-row

  bf16x8 qf[2][2];
#pragma unroll
  for (int a = 0; a < 2; ++a) {
    const bf16_t* qp = Q + (size_t)(b * kT + qr0 + a * 16 + l15) * kC + h * kHD + l4 * 8;
    qf[a][0] = *reinterpret_cast<const bf16x8*>(qp);
    qf[a][1] = *reinterpret_cast<const bf16x8*>(qp + 32);
#pragma unroll
    for (int j = 0; j < 8; ++j) {
      qf[a][0][j] = (bf16_t)((float)qf[a][0][j] * 0.1803368801111204f);
      qf[a][1][j] = (bf16_t)((float)qf[a][1][j] * 0.1803368801111204f);
    }
  }
  bf16x8 ones;
#pragma unroll
  for (int j = 0; j < 8; ++j) ones[j] = (bf16_t)1.0f;

  f32x4 po[2][4] = {};
  f32x4 po_s[2] = {};
  float mrun[2];
  mrun[0] = mrun[1] = -3.0e38f;

  const int nkt = CAUSAL ? 4 * qseg + 4 : (kT / 64);
  const int klim = CAUSAL ? ((qr0 + 31) >> 6) : (1 << 30);

  const int lr = lane >> 3;
  const int cswz = ((lane & 7) ^ lr) * 8;
  // running staging pointers (staged kt advances by 1 per stage call)
  const bf16_t* kStage = Kb + (size_t)(b * kT + w * 8 + lr) * kC + h * kHD + cswz;
  const bf16_t* vStage = Vt + (size_t)(h * kHD + w * 8 + lr) * (kB * kT) + b * kT + cswz;

  auto stage = [&](int buf) {
    gload_lds16(kStage, &Ks[buf][w * 512]);
    gload_lds16(vStage, &Vs[buf][w * 512]);
    kStage += (size_t)64 * kC;
    vStage += 64;
  };

  const int cbx = (l15 & 7) * 16;
  const int rb0 = ((l4 * 16) ^ cbx) >> 1;
  const int rb1 = ((64 | (l4 * 16)) ^ cbx) >> 1;

  stage(0);
  asm volatile("s_waitcnt vmcnt(0)" ::: "memory");
  __builtin_amdgcn_s_barrier();

  int buf = 0;
  for (int kt = 0; kt < nkt; ++kt) {
    if (kt + 1 < nkt) stage(buf ^ 1);
    if (kt <= klim) {
      bf16x8 kf[4][2];
#pragma unroll
      for (int sub = 0; sub < 4; ++sub) {
        kf[sub][0] = *reinterpret_cast<const bf16x8*>(&Ks[buf][(sub * 16 + l15) * 64 + rb0]);
        kf[sub][1] = *reinterpret_cast<const bf16x8*>(&Ks[buf][(sub * 16 + l15) * 64 + rb1]);
      }
      bf16x8 vf[2][4];
#pragma unroll
      for (int n = 0; n < 4; ++n) {
        vf[0][n] = *reinterpret_cast<const bf16x8*>(&Vs[buf][(n * 16 + l15) * 64 + rb0]);
        vf[1][n] = *reinterpret_cast<const bf16x8*>(&Vs[buf][(n * 16 + l15) * 64 + rb1]);
      }

      f32x4 s[2][4] = {};
      __builtin_amdgcn_s_setprio(1);
#pragma unroll
      for (int a = 0; a < 2; ++a)
#pragma unroll
        for (int sub = 0; sub < 4; ++sub) {
          s[a][sub] = mfma16(kf[sub][0], qf[a][0], s[a][sub]);
          s[a][sub] = mfma16(kf[sub][1], qf[a][1], s[a][sub]);
        }
      __builtin_amdgcn_s_setprio(0);
      if (CAUSAL && kt == klim) {
#pragma unroll
        for (int a = 0; a < 2; ++a) {
          const int qrow = qr0 + a * 16 + l15;
#pragma unroll
          for (int sub = 0; sub < 4; ++sub)
#pragma unroll
            for (int r = 0; r < 4; ++r) {
              const int key = kt * 64 + sub * 16 + l4 * 4 + r;
              if (key > qrow) s[a][sub][r] = -3.0e38f;
            }
        }
      }
#pragma unroll
      for (int a = 0; a < 2; ++a) {
        float t0 = fmaxf(fmaxf(s[a][0][0], s[a][0][1]), fmaxf(s[a][0][2], s[a][0][3]));
        float t1 = fmaxf(fmaxf(s[a][1][0], s[a][1][1]), fmaxf(s[a][1][2], s[a][1][3]));
        float t2 = fmaxf(fmaxf(s[a][2][0], s[a][2][1]), fmaxf(s[a][2][2], s[a][2][3]));
        float t3 = fmaxf(fmaxf(s[a][3][0], s[a][3][1]), fmaxf(s[a][3][2], s[a][3][3]));
        float v = fmaxf(fmaxf(t0, t1), fmaxf(t2, t3));
        v = fmaxf(v, __shfl_xor(v, 16, 64));
        v = fmaxf(v, __shfl_xor(v, 32, 64));
        if (!__all(v <= mrun[a] + 8.f)) {
          const float mnew = fmaxf(mrun[a], v);
          const float corr = ex2(mrun[a] - mnew);
          mrun[a] = mnew;
#pragma unroll
          for (int n = 0; n < 4; ++n)
#pragma unroll
            for (int r = 0; r < 4; ++r) po[a][n][r] *= corr;
#pragma unroll
          for (int r = 0; r < 4; ++r) po_s[a][r] *= corr;
        }
#pragma unroll
        for (int sub = 0; sub < 4; ++sub) {
          bf16x4 pk;
#pragma unroll
          for (int r = 0; r < 4; ++r) pk[r] = (bf16_t)ex2(s[a][sub][r] - mrun[a]);
          *reinterpret_cast<bf16x4*>(&P[w][a * 16 + l15][sub * 16 + l4 * 4]) = pk;
        }
      }
#pragma unroll
      for (int a = 0; a < 2; ++a)
#pragma unroll
        for (int kk = 0; kk < 2; ++kk) {
          const bf16x8 pf =
              *reinterpret_cast<const bf16x8*>(&P[w][a * 16 + l15][kk * 32 + l4 * 8]);
          __builtin_amdgcn_s_setprio(1);
#pragma unroll
          for (int n = 0; n < 4; ++n) po[a][n] = mfma16(vf[kk][n], pf, po[a][n]);
          po_s[a] = mfma16(ones, pf, po_s[a]);
          __builtin_amdgcn_s_setprio(0);
        }
    }
    asm volatile("s_waitcnt vmcnt(0)" ::: "memory");
    __builtin_amdgcn_s_barrier();
    buf ^= 1;
  }

#pragma unroll
  for (int a = 0; a < 2; ++a) {
    const float inv = 1.f / po_s[a][0];
#pragma unroll
    for (int n = 0; n < 4; ++n) {
      bf16x4 ov;
#pragma unroll
      for (int r = 0; r < 4; ++r) ov[r] = (bf16_t)(po[a][n][r] * inv);
      *reinterpret_cast<bf16x4*>(
          O + (size_t)(b * kT + qr0 + a * 16 + l15) * kC + h * kHD + n * 16 + l4 * 4) = ov;
    }
  }
}

// ---------------- launcher ----------------
extern "C" void kernel_launch(void* const* d_in, const int* in_sizes, int n_in,
                              void* d_out, int out_size, void* d_ws, size_t ws_size,
                              hipStream_t stream) {
  const float* x      = (const float*)d_in[0];
  const float* enc    = (const float*)d_in[1];
  const float* sa_wq  = (const float*)d_in[2];
  const float* sa_wk  = (const float*)d_in[3];
  const float* sa_wv  = (const float*)d_in[4];
  const float* sa_pw  = (const float*)d_in[5];
  const float* sa_pb  = (const float*)d_in[6];
  const float* ca_wq  = (const float*)d_in[7];
  const float* ca_wk  = (const float*)d_in[8];
  const float* ca_wv  = (const float*)d_in[9];
  const float* ca_pw  = (const float*)d_in[10];
  const float* ca_pb  = (const float*)d_in[11];
  const float* ff_w1  = (const float*)d_in[12];
  const float* ff_b1  = (const float*)d_in[13];
  const float* ff_w2  = (const float*)d_in[14];
  const float* ff_b2  = (const float*)d_in[15];
  const float* ln1_g  = (const float*)d_in[16];
  const float* ln1_b  = (const float*)d_in[17];
  const float* ln2_g  = (const float*)d_in[18];
  const float* ln2_b  = (const float*)d_in[19];
  const float* ln3_g  = (const float*)d_in[20];
  const float* ln3_b  = (const float*)d_in[21];

  const size_t ACT_BF = (size_t)kM * kC * 2;   // 16 MiB
  const size_t ACT_F  = (size_t)kM * kC * 4;   // 32 MiB
  const size_t W_BF   = (size_t)kC * kC * 2;
  const size_t FF_BF  = (size_t)kC * kFF * 2;
  const size_t H_BF   = (size_t)kM * kFF * 2;

  char* ws = (char*)d_ws;
  size_t off = 0;
  auto alloc = [&](size_t bytes) {
    char* p = ws + off;
    off += (bytes + 255) & ~(size_t)255;
    return p;
  };
  bf16_t* xbf   = (bf16_t*)alloc(ACT_BF);
  bf16_t* encbf = (bf16_t*)alloc(ACT_BF);
  bf16_t* lnbuf = (bf16_t*)alloc(ACT_BF);
  bf16_t* wsaq  = (bf16_t*)alloc(W_BF);
  bf16_t* wkvsa = (bf16_t*)alloc(2 * W_BF);  // [2048][1024]: wk^T rows, then wv^T rows
  bf16_t* wsap  = (bf16_t*)alloc(W_BF);
  bf16_t* wcaq  = (bf16_t*)alloc(W_BF);
  bf16_t* wkvca = (bf16_t*)alloc(2 * W_BF);
  bf16_t* wcap  = (bf16_t*)alloc(W_BF);
  bf16_t* wff1t = (bf16_t*)alloc(FF_BF);   // [4096][1024]
  bf16_t* wff2t = (bf16_t*)alloc(FF_BF);   // [1024][4096]
  float*  rbuf  = (float*)alloc(ACT_F);    // residual chain (f32)
  char*   scr   = alloc(5 * ACT_BF > H_BF ? 5 * ACT_BF : H_BF);
  bf16_t* qbf   = (bf16_t*)scr;
  bf16_t* kbf   = (bf16_t*)(scr + ACT_BF);
  bf16_t* vtbf  = (bf16_t*)(scr + 3 * ACT_BF);
  bf16_t* aobf  = (bf16_t*)(scr + 4 * ACT_BF);
  bf16_t* hbf   = (bf16_t*)scr;            // FFN hidden reuses q..ao region

  const dim3 blk512(512), blk256(256), blkT(32, 8);
  const int n4 = kM * kC / 4;
  const dim3 gGemmC(kC / 128, kM / 128);       // (8, 64) = 512
  const dim3 gGemmKV(2 * kC / 128, kM / 128);  // (16, 64) = 1024
  const dim3 gGemmF(kFF / 128, kM / 128);      // (32, 64) = 2048
  const dim3 gAttn(kB, kH, kT / 256);          // (8, 16, 4) — 8 waves, 256 q-rows/block
  const uint32_t LDSB = 65536;                 // 64KB -> 2 blocks/CU

  hipFuncSetAttribute((const void*)k_gemm2<0, true>,  hipFuncAttributeMaxDynamicSharedMemorySize, LDSB);
  hipFuncSetAttribute((const void*)k_gemm2<1, true>,  hipFuncAttributeMaxDynamicSharedMemorySize, LDSB);
  hipFuncSetAttribute((const void*)k_gemm2<1, false>, hipFuncAttributeMaxDynamicSharedMemorySize, LDSB);
  hipFuncSetAttribute((const void*)k_gemm2<2, true>,  hipFuncAttributeMaxDynamicSharedMemorySize, LDSB);
  hipFuncSetAttribute((const void*)k_gemm2<4, true>,  hipFuncAttributeMaxDynamicSharedMemorySize, LDSB);

  // ---- input casts + weight transposes ----
  k_cast_bf16<<<n4 / 256, blk256, 0, stream>>>(enc, encbf, n4);
  Trans8Args ta;
  ta.src[0] = sa_wq; ta.dst[0] = wsaq;
  ta.src[1] = sa_wk; ta.dst[1] = wkvsa;
  ta.src[2] = sa_wv; ta.dst[2] = wkvsa + (size_t)kC * kC;
  ta.src[3] = sa_pw; ta.dst[3] = wsap;
  ta.src[4] = ca_wq; ta.dst[4] = wcaq;
  ta.src[5] = ca_wk; ta.dst[5] = wkvca;
  ta.src[6] = ca_wv; ta.dst[6] = wkvca + (size_t)kC * kC;
  ta.src[7] = ca_pw; ta.dst[7] = wcap;
  k_transpose_cast8<<<dim3(kC / 32, kC / 32, 8), blkT, 0, stream>>>(ta);
  k_transpose_cast<<<dim3(kFF / 32, kC / 32), blkT, 0, stream>>>(ff_w1, wff1t, kC, kFF);
  k_transpose_cast<<<dim3(kC / 32, kFF / 32), blkT, 0, stream>>>(ff_w2, wff2t, kFF, kC);

  // ---- self-attention (q from ln1(x), k/v from raw x, causal) ----
  k_ln<true><<<kM, blk256, 0, stream>>>(x, ln1_g, ln1_b, lnbuf, xbf);
  k_gemm2<0, true><<<gGemmC, blk256, LDSB, stream>>>(lnbuf, wsaq, nullptr, nullptr, nullptr, qbf, nullptr, kM, kC, kC);
  k_gemm2<4, true><<<gGemmKV, blk256, LDSB, stream>>>(xbf, wkvsa, nullptr, nullptr, nullptr, kbf, vtbf, kM, 2 * kC, kC);
  k_attn<true><<<gAttn, blk512, 0, stream>>>(qbf, kbf, vtbf, aobf);
  k_gemm2<1, true><<<gGemmC, blk256, LDSB, stream>>>(aobf, wsap, sa_pb, x, rbuf, nullptr, nullptr, kM, kC, kC);

  // ---- cross-attention (q from ln2(r), k/v from encoder_output) ----
  k_ln<false><<<kM, blk256, 0, stream>>>(rbuf, ln2_g, ln2_b, lnbuf, nullptr);
  k_gemm2<0, true><<<gGemmC, blk256, LDSB, stream>>>(lnbuf, wcaq, nullptr, nullptr, nullptr, qbf, nullptr, kM, kC, kC);
  k_gemm2<4, true><<<gGemmKV, blk256, LDSB, stream>>>(encbf, wkvca, nullptr, nullptr, nullptr, kbf, vtbf, kM, 2 * kC, kC);
  k_attn<false><<<gAttn, blk512, 0, stream>>>(qbf, kbf, vtbf, aobf);
  k_gemm2<1, true><<<gGemmC, blk256, LDSB, stream>>>(aobf, wcap, ca_pb, rbuf, rbuf, nullptr, nullptr, kM, kC, kC);

  // ---- feed-forward ----
  k_ln<false><<<kM, blk256, 0, stream>>>(rbuf, ln3_g, ln3_b, lnbuf, nullptr);
  k_gemm2<2, true><<<gGemmF, blk256, LDSB, stream>>>(lnbuf, wff1t, ff_b1, nullptr, nullptr, hbf, nullptr, kM, kFF, kC);
  k_gemm2<1, false><<<gGemmC, blk256, LDSB, stream>>>(hbf, wff2t, ff_b2, rbuf, (float*)d_out, nullptr, nullptr, kM, kC, kFF);

  (void)in_sizes; (void)n_in; (void)out_size; (void)ws_size;
}